// Round 1
// baseline (584.502 us; speedup 1.0000x reference)
//
#include <hip/hip_runtime.h>

// AttentionModule: 3-layer sigmoid-QKV attention, B=64 N=1024 R=128 D=64 H=64.
// Strategy: bf16 MFMA (16x16x32) everywhere; activations stored transposed
// (N x feat, feat contiguous) so all MFMA operand loads are contiguous 16B.
// Flash-style attention with static-bound softmax (no online max needed since
// S <= 128/scale exactly), fused output projection + silu + mask in epilogue.

typedef __bf16 bf16;
typedef bf16 bf16x8 __attribute__((ext_vector_type(8)));
typedef float f32x4 __attribute__((ext_vector_type(4)));

#define MFMA16(a, b, c) __builtin_amdgcn_mfma_f32_16x16x32_bf16(a, b, c, 0, 0, 0)

__device__ __forceinline__ float fast_sigmoid(float x) {
  return __builtin_amdgcn_rcpf(1.0f + __expf(-x));
}

// ---------------- prep: per-batch scale + weight fp32->bf16 ----------------
__global__ __launch_bounds__(256) void prep_kernel(
    const int* __restrict__ L,
    const float* __restrict__ wq0, const float* __restrict__ wqr,
    const float* __restrict__ wk0, const float* __restrict__ wkr,
    const float* __restrict__ wv0, const float* __restrict__ wvr,
    const float* __restrict__ wor, const float* __restrict__ wo_last,
    float* __restrict__ scale_inv, bf16* __restrict__ wbf) {
  __shared__ int red[256];
  const int blk = blockIdx.x;
  const int tid = threadIdx.x;
  if (blk < 64) {
    int cnt = 0;
    for (int n = tid; n < 1024; n += 256) cnt += (L[blk * 1024 + n] >= 1) ? 1 : 0;
    red[tid] = cnt;
    __syncthreads();
    for (int s = 128; s > 0; s >>= 1) {
      if (tid < s) red[tid] += red[tid + s];
      __syncthreads();
    }
    if (tid == 0) scale_inv[blk] = rsqrtf((float)red[0] + 1.0f);
  } else {
    for (int i = (blk - 64) * 256 + tid; i < 163840; i += 64 * 256) {
      float v;
      if      (i <   8192) v = wq0[i];
      else if (i <  40960) v = wqr[i - 8192];
      else if (i <  49152) v = wk0[i - 40960];
      else if (i <  81920) v = wkr[i - 49152];
      else if (i <  90112) v = wv0[i - 81920];
      else if (i < 122880) v = wvr[i - 90112];
      else if (i < 155648) v = wor[i - 122880];
      else                 v = wo_last[i - 155648];
      wbf[i] = (bf16)v;
    }
  }
}

// ---------------- transpose x (B,D,N) f32 -> xT (B,N,D) bf16 ----------------
__global__ __launch_bounds__(256) void xpose_kernel(const float* __restrict__ x,
                                                    bf16* __restrict__ xT) {
  __shared__ float tile[64][65];
  const int blk = blockIdx.x;
  const int b = blk >> 4;
  const int n0 = (blk & 15) * 64;
  const int tid = threadIdx.x;
  {
    const int nl = tid & 63, dbase = (tid >> 6) * 16;
#pragma unroll
    for (int i = 0; i < 16; i++) {
      int d = dbase + i;
      tile[d][nl] = x[(size_t)(b * 64 + d) * 1024 + n0 + nl];
    }
  }
  __syncthreads();
  {
    const int dl = tid & 63, nbase = (tid >> 6) * 16;
#pragma unroll
    for (int i = 0; i < 16; i++) {
      int n = nbase + i;
      xT[(size_t)(b * 1024 + n0 + n) * 64 + dl] = (bf16)tile[dl][n];
    }
  }
}

// ---------------- QKV: Qt,Kt (N,R) and V (R,N), sigmoid fused ----------------
// C[n][r] = sum_d inpT[n][d] * W[r][d]  (Q,K);  C[r][n] = sum_d W[r][d]*inpT[n][d] (V)
template <int DIN>
__global__ __launch_bounds__(256) void qkv_kernel(
    const bf16* __restrict__ inpT,
    const bf16* __restrict__ Wq, const bf16* __restrict__ Wk,
    const bf16* __restrict__ Wv,
    bf16* __restrict__ Qt, bf16* __restrict__ Kt, bf16* __restrict__ Vn) {
  constexpr int LS = DIN + 8;   // padded LDS stride (272B/144B: 16B-aligned, +4 banks/row)
  constexpr int KS = DIN / 32;  // MFMA k-steps
  __shared__ __attribute__((aligned(16))) bf16 inp_lds[64 * LS];
  const int tid = threadIdx.x;
  const int lane = tid & 63, wv = tid >> 6;
  const int la = lane & 15, kg = (lane >> 4) * 8;
  const int crow = (lane >> 4) * 4;
  const int b = blockIdx.x >> 4;
  const int q0 = (blockIdx.x & 15) * 64;

  {
    constexpr int CPR = DIN / 8;
    for (int i = tid; i < 64 * CPR; i += 256) {
      int row = i / CPR, c = i % CPR;
      *(bf16x8*)&inp_lds[row * LS + c * 8] =
          *(const bf16x8*)(inpT + (size_t)(b * 1024 + q0 + row) * DIN + c * 8);
    }
  }
  __syncthreads();

  bf16x8 afrag[KS];
#pragma unroll
  for (int ks = 0; ks < KS; ks++)
    afrag[ks] = *(const bf16x8*)&inp_lds[(16 * wv + la) * LS + ks * 32 + kg];

  const bf16* Wqk[2] = {Wq, Wk};
  bf16* Oqk[2] = {Qt, Kt};
#pragma unroll
  for (int which = 0; which < 2; which++) {
    const bf16* W = Wqk[which];
    bf16* Out = Oqk[which];
#pragma unroll
    for (int t = 0; t < 8; t++) {
      f32x4 acc = {0.f, 0.f, 0.f, 0.f};
#pragma unroll
      for (int ks = 0; ks < KS; ks++) {
        bf16x8 bfr = *(const bf16x8*)(W + (size_t)(la + 16 * t) * DIN + ks * 32 + kg);
        acc = MFMA16(afrag[ks], bfr, acc);
      }
#pragma unroll
      for (int r = 0; r < 4; r++) {
        int n = q0 + 16 * wv + crow + r;
        Out[(size_t)b * 1024 * 128 + (size_t)n * 128 + la + 16 * t] =
            (bf16)fast_sigmoid(acc[r]);
      }
    }
  }
  // V in natural (R,N): C[r][n], A = Wv rows, B = inpT rows
#pragma unroll
  for (int s = 0; s < 2; s++) {
    int rbase = 16 * wv + 64 * s;
    bf16x8 af[KS];
#pragma unroll
    for (int ks = 0; ks < KS; ks++)
      af[ks] = *(const bf16x8*)(Wv + (size_t)(rbase + la) * DIN + ks * 32 + kg);
#pragma unroll
    for (int t = 0; t < 4; t++) {
      f32x4 acc = {0.f, 0.f, 0.f, 0.f};
#pragma unroll
      for (int ks = 0; ks < KS; ks++) {
        bf16x8 bfr = *(const bf16x8*)&inp_lds[(16 * t + la) * LS + ks * 32 + kg];
        acc = MFMA16(af[ks], bfr, acc);
      }
#pragma unroll
      for (int r = 0; r < 4; r++) {
        int rr = rbase + crow + r;
        int n = q0 + 16 * t + la;
        Vn[(size_t)b * 128 * 1024 + (size_t)rr * 1024 + n] = (bf16)fast_sigmoid(acc[r]);
      }
    }
  }
}

// ---------------- flash attention + fused projection/silu/mask ----------------
__global__ __launch_bounds__(256) void flash_kernel(
    const bf16* __restrict__ Qt, const bf16* __restrict__ Kt,
    const bf16* __restrict__ Vn, const float* __restrict__ scale_inv,
    const int* __restrict__ L, const bf16* __restrict__ Wo,
    void* __restrict__ outp, int last) {
  __shared__ __attribute__((aligned(16))) bf16 K_lds[64 * 136];
  __shared__ __attribute__((aligned(16))) bf16 V_lds[128 * 72];
  __shared__ __attribute__((aligned(16))) bf16 P_lds[64 * 72];
  __shared__ __attribute__((aligned(16))) bf16 O_lds[64 * 136];

  const int tid = threadIdx.x;
  const int lane = tid & 63, wv = tid >> 6;
  const int la = lane & 15, kg = (lane >> 4) * 8;
  const int crow = (lane >> 4) * 4;
  const int b = blockIdx.x >> 4;
  const int q0 = (blockIdx.x & 15) * 64;

  const float inv = scale_inv[b];
  const float bound = 128.0f * inv;  // S/scale <= R/scale exactly (Q,K in (0,1))

  bf16x8 qf[4];
#pragma unroll
  for (int ks = 0; ks < 4; ks++)
    qf[ks] = *(const bf16x8*)(Qt + (size_t)(b * 1024 + q0 + 16 * wv + la) * 128 +
                              ks * 32 + kg);

  f32x4 acc_o[8];
#pragma unroll
  for (int t = 0; t < 8; t++) acc_o[t] = {0.f, 0.f, 0.f, 0.f};
  float rs[4] = {0.f, 0.f, 0.f, 0.f};

  for (int it = 0; it < 16; it++) {
    const int m0 = it * 64;
    __syncthreads();
    for (int i = tid; i < 64 * 16; i += 256) {
      int row = i >> 4, c = i & 15;
      *(bf16x8*)&K_lds[row * 136 + c * 8] =
          *(const bf16x8*)(Kt + (size_t)(b * 1024 + m0 + row) * 128 + c * 8);
    }
    for (int i = tid; i < 128 * 8; i += 256) {
      int row = i >> 3, c = i & 7;
      *(bf16x8*)&V_lds[row * 72 + c * 8] =
          *(const bf16x8*)(Vn + (size_t)(b * 128 + row) * 1024 + m0 + c * 8);
    }
    __syncthreads();

    // S strip (16 rows x 64 cols per wave) -> P = exp(S/scale - bound)
#pragma unroll
    for (int t = 0; t < 4; t++) {
      f32x4 acc = {0.f, 0.f, 0.f, 0.f};
#pragma unroll
      for (int ks = 0; ks < 4; ks++) {
        bf16x8 bfr = *(const bf16x8*)&K_lds[(la + 16 * t) * 136 + ks * 32 + kg];
        acc = MFMA16(qf[ks], bfr, acc);
      }
#pragma unroll
      for (int r = 0; r < 4; r++) {
        float p = __expf(acc[r] * inv - bound);
        rs[r] += p;
        P_lds[(16 * wv + crow + r) * 72 + la + 16 * t] = (bf16)p;
      }
    }
    // O[n][r] += P @ V^T   (A = P rows from LDS, B = V natural rows)
    bf16x8 pa[2];
#pragma unroll
    for (int k2 = 0; k2 < 2; k2++)
      pa[k2] = *(const bf16x8*)&P_lds[(16 * wv + la) * 72 + k2 * 32 + kg];
#pragma unroll
    for (int t = 0; t < 8; t++) {
#pragma unroll
      for (int k2 = 0; k2 < 2; k2++) {
        bf16x8 vb = *(const bf16x8*)&V_lds[(la + 16 * t) * 72 + k2 * 32 + kg];
        acc_o[t] = MFMA16(pa[k2], vb, acc_o[t]);
      }
    }
  }

  // finalize row sums (reduce over the 16 lanes holding a row's columns)
#pragma unroll
  for (int r = 0; r < 4; r++) {
#pragma unroll
    for (int off = 1; off < 16; off <<= 1) rs[r] += __shfl_xor(rs[r], off, 64);
    rs[r] = 1.0f / fmaxf(rs[r], 1e-30f);
  }
#pragma unroll
  for (int t = 0; t < 8; t++) {
#pragma unroll
    for (int r = 0; r < 4; r++) {
      O_lds[(16 * wv + crow + r) * 136 + la + 16 * t] = (bf16)(acc_o[t][r] * rs[r]);
    }
  }
  __syncthreads();

  if (!last) {
    // inpT_next[n][o] = mask[n] * silu( sum_r O[n][r] * Wo[o][r] )
    bf16* inpT = (bf16*)outp;
    bf16x8 oa[4];
#pragma unroll
    for (int ks = 0; ks < 4; ks++)
      oa[ks] = *(const bf16x8*)&O_lds[(16 * wv + la) * 136 + ks * 32 + kg];
    float lmask[4];
#pragma unroll
    for (int r = 0; r < 4; r++)
      lmask[r] = (float)L[b * 1024 + q0 + 16 * wv + crow + r];
#pragma unroll
    for (int t = 0; t < 8; t++) {
      f32x4 acc = {0.f, 0.f, 0.f, 0.f};
#pragma unroll
      for (int ks = 0; ks < 4; ks++) {
        bf16x8 wb = *(const bf16x8*)(Wo + (size_t)(la + 16 * t) * 128 + ks * 32 + kg);
        acc = MFMA16(oa[ks], wb, acc);
      }
#pragma unroll
      for (int r = 0; r < 4; r++) {
        float xv = acc[r];
        float y = xv * fast_sigmoid(xv) * lmask[r];
        int n = q0 + 16 * wv + crow + r;
        inpT[(size_t)(b * 1024 + n) * 128 + la + 16 * t] = (bf16)y;
      }
    }
  } else {
    // out[h][n] = silu( sum_r Wo[h][r] * O[n][r] ), fp32 natural layout
    float* outf = (float*)outp;
    bf16x8 wa[4];
#pragma unroll
    for (int ks = 0; ks < 4; ks++)
      wa[ks] = *(const bf16x8*)(Wo + (size_t)(16 * wv + la) * 128 + ks * 32 + kg);
#pragma unroll
    for (int t = 0; t < 4; t++) {
      f32x4 acc = {0.f, 0.f, 0.f, 0.f};
#pragma unroll
      for (int ks = 0; ks < 4; ks++) {
        bf16x8 ob = *(const bf16x8*)&O_lds[(la + 16 * t) * 136 + ks * 32 + kg];
        acc = MFMA16(wa[ks], ob, acc);
      }
#pragma unroll
      for (int r = 0; r < 4; r++) {
        float xv = acc[r];
        float y = xv * fast_sigmoid(xv);
        int h = 16 * wv + crow + r;
        outf[(size_t)(b * 64 + h) * 1024 + q0 + la + 16 * t] = y;
      }
    }
  }
}

// ---------------- host launch ----------------
extern "C" void kernel_launch(void* const* d_in, const int* in_sizes, int n_in,
                              void* d_out, int out_size, void* d_ws, size_t ws_size,
                              hipStream_t stream) {
  const float* x = (const float*)d_in[0];
  const int* L = (const int*)d_in[1];
  const float* wq0 = (const float*)d_in[2];
  const float* wqr = (const float*)d_in[3];
  const float* wk0 = (const float*)d_in[4];
  const float* wkr = (const float*)d_in[5];
  const float* wv0 = (const float*)d_in[6];
  const float* wvr = (const float*)d_in[7];
  const float* wor = (const float*)d_in[8];
  const float* wo_last = (const float*)d_in[9];

  // workspace layout (bytes)
  char* ws = (char*)d_ws;
  float* scale_inv = (float*)(ws + 0);            //    256 B
  bf16* wbf = (bf16*)(ws + 4096);                 // 327680 B
  bf16* xT = (bf16*)(ws + 335872);                //   8 MB  (B,N,64)
  bf16* inpT = (bf16*)(ws + 8724480);             //  16 MB  (B,N,128)
  bf16* Qt = (bf16*)(ws + 25501696);              //  16 MB  (B,N,128)
  bf16* Kt = (bf16*)(ws + 42278912);              //  16 MB  (B,N,128)
  bf16* Vn = (bf16*)(ws + 59056128);              //  16 MB  (B,128,N)
  if (ws_size < 75833344) return;                 // workspace too small

  prep_kernel<<<128, 256, 0, stream>>>(L, wq0, wqr, wk0, wkr, wv0, wvr, wor,
                                       wo_last, scale_inv, wbf);
  xpose_kernel<<<1024, 256, 0, stream>>>(x, xT);

  // bf16 weight offsets (elements) inside wbf
  // wq0@0 wqr@8192 wk0@40960 wkr@49152 wv0@81920 wvr@90112 wor@122880 wo_last@155648
  for (int l = 0; l < 3; l++) {
    const bf16* Wq = (l == 0) ? wbf + 0 : wbf + 8192 + (size_t)(l - 1) * 16384;
    const bf16* Wk = (l == 0) ? wbf + 40960 : wbf + 49152 + (size_t)(l - 1) * 16384;
    const bf16* Wv = (l == 0) ? wbf + 81920 : wbf + 90112 + (size_t)(l - 1) * 16384;
    if (l == 0) {
      qkv_kernel<64><<<1024, 256, 0, stream>>>(xT, Wq, Wk, Wv, Qt, Kt, Vn);
    } else {
      qkv_kernel<128><<<1024, 256, 0, stream>>>(inpT, Wq, Wk, Wv, Qt, Kt, Vn);
    }
    const bf16* Wo = (l < 2) ? wbf + 122880 + (size_t)l * 16384 : wbf + 155648;
    void* outp = (l < 2) ? (void*)inpT : (void*)d_out;
    flash_kernel<<<1024, 256, 0, stream>>>(Qt, Kt, Vn, scale_inv, L, Wo, outp,
                                           (l == 2) ? 1 : 0);
  }
}

// Round 2
// 419.314 us; speedup vs baseline: 1.3939x; 1.3939x over previous
//
#include <hip/hip_runtime.h>

// AttentionModule: 3-layer sigmoid-QKV attention, B=64 N=1024 R=128 D=64 H=64.
// bf16 MFMA 16x16x32 everywhere. Flash-style attention with static-bound
// softmax (S <= 128/scale exactly since Q,K in (0,1)).
// R2: latency-bound fix -- LDS 62->44KB (3 blocks/CU), register-prefetch
// pipeline for K/V staging, S^T orientation (packed b64 P writes, wave-private
// P, 2-shuffle rowsum), exp2-based exp, packed qkv stores.

typedef __bf16 bf16;
typedef bf16 bf16x4 __attribute__((ext_vector_type(4)));
typedef bf16 bf16x8 __attribute__((ext_vector_type(8)));
typedef float f32x4 __attribute__((ext_vector_type(4)));

#define MFMA16(a, b, c) __builtin_amdgcn_mfma_f32_16x16x32_bf16(a, b, c, 0, 0, 0)
#define LOG2E 1.44269504f

__device__ __forceinline__ float fast_sigmoid(float x) {
  // 1/(1+2^(-x*log2e))
  return __builtin_amdgcn_rcpf(1.0f + exp2f(-LOG2E * x));
}

// ---------------- prep: per-batch scale + weight fp32->bf16 ----------------
__global__ __launch_bounds__(256) void prep_kernel(
    const int* __restrict__ L,
    const float* __restrict__ wq0, const float* __restrict__ wqr,
    const float* __restrict__ wk0, const float* __restrict__ wkr,
    const float* __restrict__ wv0, const float* __restrict__ wvr,
    const float* __restrict__ wor, const float* __restrict__ wo_last,
    float* __restrict__ scale_inv, bf16* __restrict__ wbf) {
  __shared__ int red[256];
  const int blk = blockIdx.x;
  const int tid = threadIdx.x;
  if (blk < 64) {
    int cnt = 0;
    for (int n = tid; n < 1024; n += 256) cnt += (L[blk * 1024 + n] >= 1) ? 1 : 0;
    red[tid] = cnt;
    __syncthreads();
    for (int s = 128; s > 0; s >>= 1) {
      if (tid < s) red[tid] += red[tid + s];
      __syncthreads();
    }
    if (tid == 0) scale_inv[blk] = rsqrtf((float)red[0] + 1.0f);
  } else {
    for (int i = (blk - 64) * 256 + tid; i < 163840; i += 64 * 256) {
      float v;
      if      (i <   8192) v = wq0[i];
      else if (i <  40960) v = wqr[i - 8192];
      else if (i <  49152) v = wk0[i - 40960];
      else if (i <  81920) v = wkr[i - 49152];
      else if (i <  90112) v = wv0[i - 81920];
      else if (i < 122880) v = wvr[i - 90112];
      else if (i < 155648) v = wor[i - 122880];
      else                 v = wo_last[i - 155648];
      wbf[i] = (bf16)v;
    }
  }
}

// ---------------- transpose x (B,D,N) f32 -> xT (B,N,D) bf16 ----------------
__global__ __launch_bounds__(256) void xpose_kernel(const float* __restrict__ x,
                                                    bf16* __restrict__ xT) {
  __shared__ float tile[64][65];
  const int blk = blockIdx.x;
  const int b = blk >> 4;
  const int n0 = (blk & 15) * 64;
  const int tid = threadIdx.x;
  {
    const int nl = tid & 63, dbase = (tid >> 6) * 16;
#pragma unroll
    for (int i = 0; i < 16; i++) {
      int d = dbase + i;
      tile[d][nl] = x[(size_t)(b * 64 + d) * 1024 + n0 + nl];
    }
  }
  __syncthreads();
  {
    const int dl = tid & 63, nbase = (tid >> 6) * 16;
#pragma unroll
    for (int i = 0; i < 16; i++) {
      int n = nbase + i;
      xT[(size_t)(b * 1024 + n0 + n) * 64 + dl] = (bf16)tile[dl][n];
    }
  }
}

// ---------------- QKV: Qt,Kt (N,R) and V (R,N), sigmoid fused ----------------
// One LDS inp-fragment set (B operand) reused across Q,K,V. A operand = W rows
// from global (L1-resident, 32KB). Q/K stores packed b64; V scalar (R,N).
template <int DIN>
__global__ __launch_bounds__(256) void qkv_kernel(
    const bf16* __restrict__ inpT,
    const bf16* __restrict__ Wq, const bf16* __restrict__ Wk,
    const bf16* __restrict__ Wv,
    bf16* __restrict__ Qt, bf16* __restrict__ Kt, bf16* __restrict__ Vn) {
  constexpr int LS = DIN + 8;
  constexpr int KS = DIN / 32;
  __shared__ __attribute__((aligned(16))) bf16 inp_lds[64 * LS];
  const int tid = threadIdx.x;
  const int lane = tid & 63, wv = tid >> 6;
  const int la = lane & 15, kg = (lane >> 4) * 8;
  const int crow = (lane >> 4) * 4;
  const int b = blockIdx.x >> 4;
  const int q0 = (blockIdx.x & 15) * 64;

  {
    constexpr int CPR = DIN / 8;
    for (int i = tid; i < 64 * CPR; i += 256) {
      int row = i / CPR, c = i % CPR;
      *(bf16x8*)&inp_lds[row * LS + c * 8] =
          *(const bf16x8*)(inpT + (size_t)(b * 1024 + q0 + row) * DIN + c * 8);
    }
  }
  __syncthreads();

  bf16x8 bfr[KS];
#pragma unroll
  for (int ks = 0; ks < KS; ks++)
    bfr[ks] = *(const bf16x8*)&inp_lds[(16 * wv + la) * LS + ks * 32 + kg];

  const int n = q0 + 16 * wv + la;  // this lane's token column

  const bf16* Wqk[2] = {Wq, Wk};
  bf16* Oqk[2] = {Qt, Kt};
#pragma unroll
  for (int which = 0; which < 2; which++) {
    const bf16* W = Wqk[which];
    bf16* Out = Oqk[which];
#pragma unroll
    for (int t = 0; t < 8; t++) {
      f32x4 acc = {0.f, 0.f, 0.f, 0.f};
#pragma unroll
      for (int ks = 0; ks < KS; ks++) {
        bf16x8 wfr = *(const bf16x8*)(W + (size_t)(la + 16 * t) * DIN + ks * 32 + kg);
        acc = MFMA16(wfr, bfr[ks], acc);
      }
      bf16x4 pk;
#pragma unroll
      for (int r = 0; r < 4; r++) pk[r] = (bf16)fast_sigmoid(acc[r]);
      *(bf16x4*)(Out + (size_t)(b * 1024 + n) * 128 + 16 * t + crow) = pk;
    }
  }
  // V in natural (R,N): C[r][n] -> scalar stores (128B segments per instr)
#pragma unroll
  for (int t = 0; t < 8; t++) {
    f32x4 acc = {0.f, 0.f, 0.f, 0.f};
#pragma unroll
    for (int ks = 0; ks < KS; ks++) {
      bf16x8 wfr = *(const bf16x8*)(Wv + (size_t)(la + 16 * t) * DIN + ks * 32 + kg);
      acc = MFMA16(wfr, bfr[ks], acc);
    }
#pragma unroll
    for (int r = 0; r < 4; r++) {
      Vn[(size_t)(b * 128 + 16 * t + crow + r) * 1024 + n] = (bf16)fast_sigmoid(acc[r]);
    }
  }
}

// ---------------- flash attention + fused projection/silu/mask ----------------
// S^T orientation: A = K rows (LDS), B = Q rows (regs). Lane la owns Q-row la:
// P writes pack to b64, rowsum is per-lane + 2 shuffles, P is wave-private.
__global__ __launch_bounds__(256, 3) void flash_kernel(
    const bf16* __restrict__ Qt, const bf16* __restrict__ Kt,
    const bf16* __restrict__ Vn, const float* __restrict__ scale_inv,
    const int* __restrict__ L, const bf16* __restrict__ Wo,
    void* __restrict__ outp, int last) {
  // LDS union: loop { K 64x136 | V 128x72 | P 4x16x72 } = 44 KB; epi O = 64x136
  __shared__ __attribute__((aligned(16))) char smem[45056];
  bf16* K_lds = (bf16*)smem;               // 17408 B
  bf16* V_lds = (bf16*)(smem + 17408);     // 18432 B
  bf16* P_all = (bf16*)(smem + 35840);     //  9216 B
  bf16* O_lds = (bf16*)smem;               // epilogue alias

  const int tid = threadIdx.x;
  const int lane = tid & 63, wv = tid >> 6;
  const int la = lane & 15, kg = (lane >> 4) * 8;
  const int crow = (lane >> 4) * 4;
  const int b = blockIdx.x >> 4;
  const int q0 = (blockIdx.x & 15) * 64;

  const float inv = scale_inv[b];
  const float inv2 = inv * LOG2E;
  const float nb2 = -128.0f * inv2;  // exp arg <= 0 always (Q,K in (0,1))

  // Q fragments (B operand): lane la -> Q row q0+16*wv+la, resident all loop
  bf16x8 qf[4];
#pragma unroll
  for (int ks = 0; ks < 4; ks++)
    qf[ks] = *(const bf16x8*)(Qt + (size_t)(b * 1024 + q0 + 16 * wv + la) * 128 +
                              ks * 32 + kg);

  // staging geometry (per-thread, fixed)
  const int krow = tid >> 4, kc8 = (tid & 15) * 8;
  const int vrow = tid >> 3, vc8 = (tid & 7) * 8;
  const bf16* kbase = Kt + (size_t)b * 1024 * 128;
  const bf16* vbase = Vn + (size_t)b * 128 * 1024;
  bf16* P_w = P_all + wv * 16 * 72;

  bf16x8 kr[4], vr[4];
#pragma unroll
  for (int p = 0; p < 4; p++) {
    kr[p] = *(const bf16x8*)(kbase + (size_t)(krow + 16 * p) * 128 + kc8);
    vr[p] = *(const bf16x8*)(vbase + (size_t)(vrow + 32 * p) * 1024 + vc8);
  }

  f32x4 acc_o[8];
#pragma unroll
  for (int t = 0; t < 8; t++) acc_o[t] = {0.f, 0.f, 0.f, 0.f};
  float rs = 0.f;

  for (int it = 0; it < 16; it++) {
    __syncthreads();  // all waves done reading previous tile
#pragma unroll
    for (int p = 0; p < 4; p++)
      *(bf16x8*)&K_lds[(krow + 16 * p) * 136 + kc8] = kr[p];
#pragma unroll
    for (int p = 0; p < 4; p++)
      *(bf16x8*)&V_lds[(vrow + 32 * p) * 72 + vc8] = vr[p];
    __syncthreads();  // tile `it` visible

    if (it < 15) {  // prefetch tile it+1 into regs; latency hides under compute
      const int m1 = (it + 1) * 64;
#pragma unroll
      for (int p = 0; p < 4; p++) {
        kr[p] = *(const bf16x8*)(kbase + (size_t)(m1 + krow + 16 * p) * 128 + kc8);
        vr[p] = *(const bf16x8*)(vbase + (size_t)(vrow + 32 * p) * 1024 + m1 + vc8);
      }
    }

    // S^T: C[m][n], m = KV col (crow+r+16t), n = Q row (la)
#pragma unroll
    for (int t = 0; t < 4; t++) {
      f32x4 acc = {0.f, 0.f, 0.f, 0.f};
#pragma unroll
      for (int ks = 0; ks < 4; ks++) {
        bf16x8 kf = *(const bf16x8*)&K_lds[(la + 16 * t) * 136 + ks * 32 + kg];
        acc = MFMA16(kf, qf[ks], acc);
      }
      bf16x4 pk;
#pragma unroll
      for (int r = 0; r < 4; r++) {
        float p = exp2f(fmaf(acc[r], inv2, nb2));
        rs += p;
        pk[r] = (bf16)p;
      }
      *(bf16x4*)&P_w[la * 72 + 16 * t + crow] = pk;  // packed b64, wave-private
    }

    // PV: O[qrow][r] += P[qrow][m] * V[r][m]
    bf16x8 pa[2];
#pragma unroll
    for (int k2 = 0; k2 < 2; k2++)
      pa[k2] = *(const bf16x8*)&P_w[la * 72 + k2 * 32 + kg];
#pragma unroll
    for (int t = 0; t < 8; t++) {
#pragma unroll
      for (int k2 = 0; k2 < 2; k2++) {
        bf16x8 vf = *(const bf16x8*)&V_lds[(la + 16 * t) * 72 + k2 * 32 + kg];
        acc_o[t] = MFMA16(pa[k2], vf, acc_o[t]);
      }
    }
  }

  // rowsum: lane owns Q-row la; combine the 4 lane-groups
  rs += __shfl_xor(rs, 16, 64);
  rs += __shfl_xor(rs, 32, 64);
  const float rinv = 1.0f / rs;
  float rinvr[4];
#pragma unroll
  for (int r = 0; r < 4; r++)
    rinvr[r] = __shfl(rinv, (lane & 48) | (crow + r), 64);

  __syncthreads();  // done with K_lds reads before O alias write
#pragma unroll
  for (int t = 0; t < 8; t++) {
#pragma unroll
    for (int r = 0; r < 4; r++) {
      O_lds[(16 * wv + crow + r) * 136 + la + 16 * t] =
          (bf16)(acc_o[t][r] * rinvr[r]);
    }
  }
  __syncthreads();

  if (!last) {
    // inpT_next[n][o] = mask[n] * silu( sum_r O[n][r] * Wo[o][r] )
    bf16* inpT = (bf16*)outp;
    bf16x8 oa[4];
#pragma unroll
    for (int ks = 0; ks < 4; ks++)
      oa[ks] = *(const bf16x8*)&O_lds[(16 * wv + la) * 136 + ks * 32 + kg];
    float lmask[4];
#pragma unroll
    for (int r = 0; r < 4; r++)
      lmask[r] = (float)L[b * 1024 + q0 + 16 * wv + crow + r];
#pragma unroll
    for (int t = 0; t < 8; t++) {
      f32x4 acc = {0.f, 0.f, 0.f, 0.f};
#pragma unroll
      for (int ks = 0; ks < 4; ks++) {
        bf16x8 wb = *(const bf16x8*)(Wo + (size_t)(la + 16 * t) * 128 + ks * 32 + kg);
        acc = MFMA16(oa[ks], wb, acc);
      }
#pragma unroll
      for (int r = 0; r < 4; r++) {
        float xv = acc[r];
        float y = xv * fast_sigmoid(xv) * lmask[r];
        int nn = q0 + 16 * wv + crow + r;
        inpT[(size_t)(b * 1024 + nn) * 128 + la + 16 * t] = (bf16)y;
      }
    }
  } else {
    // out[h][n] = silu( sum_r Wo[h][r] * O[n][r] ), fp32 natural layout
    float* outf = (float*)outp;
    bf16x8 wa[4];
#pragma unroll
    for (int ks = 0; ks < 4; ks++)
      wa[ks] = *(const bf16x8*)(Wo + (size_t)(16 * wv + la) * 128 + ks * 32 + kg);
#pragma unroll
    for (int t = 0; t < 4; t++) {
      f32x4 acc = {0.f, 0.f, 0.f, 0.f};
#pragma unroll
      for (int ks = 0; ks < 4; ks++) {
        bf16x8 ob = *(const bf16x8*)&O_lds[(la + 16 * t) * 136 + ks * 32 + kg];
        acc = MFMA16(wa[ks], ob, acc);
      }
#pragma unroll
      for (int r = 0; r < 4; r++) {
        float xv = acc[r];
        float y = xv * fast_sigmoid(xv);
        int h = 16 * wv + crow + r;
        outf[(size_t)(b * 64 + h) * 1024 + q0 + la + 16 * t] = y;
      }
    }
  }
}

// ---------------- host launch ----------------
extern "C" void kernel_launch(void* const* d_in, const int* in_sizes, int n_in,
                              void* d_out, int out_size, void* d_ws, size_t ws_size,
                              hipStream_t stream) {
  const float* x = (const float*)d_in[0];
  const int* L = (const int*)d_in[1];
  const float* wq0 = (const float*)d_in[2];
  const float* wqr = (const float*)d_in[3];
  const float* wk0 = (const float*)d_in[4];
  const float* wkr = (const float*)d_in[5];
  const float* wv0 = (const float*)d_in[6];
  const float* wvr = (const float*)d_in[7];
  const float* wor = (const float*)d_in[8];
  const float* wo_last = (const float*)d_in[9];

  // workspace layout (bytes)
  char* ws = (char*)d_ws;
  float* scale_inv = (float*)(ws + 0);            //    256 B
  bf16* wbf = (bf16*)(ws + 4096);                 // 327680 B
  bf16* xT = (bf16*)(ws + 335872);                //   8 MB  (B,N,64)
  bf16* inpT = (bf16*)(ws + 8724480);             //  16 MB  (B,N,128)
  bf16* Qt = (bf16*)(ws + 25501696);              //  16 MB  (B,N,128)
  bf16* Kt = (bf16*)(ws + 42278912);              //  16 MB  (B,N,128)
  bf16* Vn = (bf16*)(ws + 59056128);              //  16 MB  (B,128,N)
  if (ws_size < 75833344) return;                 // workspace too small

  prep_kernel<<<128, 256, 0, stream>>>(L, wq0, wqr, wk0, wkr, wv0, wvr, wor,
                                       wo_last, scale_inv, wbf);
  xpose_kernel<<<1024, 256, 0, stream>>>(x, xT);

  // bf16 weight offsets (elements) inside wbf
  for (int l = 0; l < 3; l++) {
    const bf16* Wq = (l == 0) ? wbf + 0 : wbf + 8192 + (size_t)(l - 1) * 16384;
    const bf16* Wk = (l == 0) ? wbf + 40960 : wbf + 49152 + (size_t)(l - 1) * 16384;
    const bf16* Wv = (l == 0) ? wbf + 81920 : wbf + 90112 + (size_t)(l - 1) * 16384;
    if (l == 0) {
      qkv_kernel<64><<<1024, 256, 0, stream>>>(xT, Wq, Wk, Wv, Qt, Kt, Vn);
    } else {
      qkv_kernel<128><<<1024, 256, 0, stream>>>(inpT, Wq, Wk, Wv, Qt, Kt, Vn);
    }
    const bf16* Wo = (l < 2) ? wbf + 122880 + (size_t)l * 16384 : wbf + 155648;
    void* outp = (l < 2) ? (void*)inpT : (void*)d_out;
    flash_kernel<<<1024, 256, 0, stream>>>(Qt, Kt, Vn, scale_inv, L, Wo, outp,
                                           (l == 2) ? 1 : 0);
  }
}

// Round 3
// 339.553 us; speedup vs baseline: 1.7214x; 1.2349x over previous
//
#include <hip/hip_runtime.h>

// AttentionModule: 3-layer sigmoid-QKV attention, B=64 N=1024 R=128 D=64 H=64.
// R3: LDS-BW fix. 32x32x16 MFMA with square per-wave tiles (2x FLOP/LDS-byte),
// Q computed in flash prologue (Qt buffer eliminated), KV-only producer kernel
// with 128-token blocks. Flash: Q operand register-resident, S^T 2x2 wave grid,
// PV (n,r) 2x2 wave grid, register prefetch of next K/V tile.

typedef __bf16 bf16;
typedef bf16 bf16x4 __attribute__((ext_vector_type(4)));
typedef bf16 bf16x8 __attribute__((ext_vector_type(8)));
typedef float f32x4 __attribute__((ext_vector_type(4)));
typedef float f32x16 __attribute__((ext_vector_type(16)));

#define MFMA32(a, b, c) __builtin_amdgcn_mfma_f32_32x32x16_bf16(a, b, c, 0, 0, 0)
#define ZERO16 {0,0,0,0,0,0,0,0,0,0,0,0,0,0,0,0}
#define LOG2E 1.44269504f

__device__ __forceinline__ float fast_sigmoid(float x) {
  return __builtin_amdgcn_rcpf(1.0f + exp2f(-LOG2E * x));
}

// ---------------- prep: per-batch scale + weight fp32->bf16 ----------------
__global__ __launch_bounds__(256) void prep_kernel(
    const int* __restrict__ L,
    const float* __restrict__ wq0, const float* __restrict__ wqr,
    const float* __restrict__ wk0, const float* __restrict__ wkr,
    const float* __restrict__ wv0, const float* __restrict__ wvr,
    const float* __restrict__ wor, const float* __restrict__ wo_last,
    float* __restrict__ scale_inv, bf16* __restrict__ wbf) {
  __shared__ int red[256];
  const int blk = blockIdx.x;
  const int tid = threadIdx.x;
  if (blk < 64) {
    int cnt = 0;
    for (int n = tid; n < 1024; n += 256) cnt += (L[blk * 1024 + n] >= 1) ? 1 : 0;
    red[tid] = cnt;
    __syncthreads();
    for (int s = 128; s > 0; s >>= 1) {
      if (tid < s) red[tid] += red[tid + s];
      __syncthreads();
    }
    if (tid == 0) scale_inv[blk] = rsqrtf((float)red[0] + 1.0f);
  } else {
    for (int i = (blk - 64) * 256 + tid; i < 163840; i += 64 * 256) {
      float v;
      if      (i <   8192) v = wq0[i];
      else if (i <  40960) v = wqr[i - 8192];
      else if (i <  49152) v = wk0[i - 40960];
      else if (i <  81920) v = wkr[i - 49152];
      else if (i <  90112) v = wv0[i - 81920];
      else if (i < 122880) v = wvr[i - 90112];
      else if (i < 155648) v = wor[i - 122880];
      else                 v = wo_last[i - 155648];
      wbf[i] = (bf16)v;
    }
  }
}

// ---------------- transpose x (B,D,N) f32 -> xT (B,N,D) bf16 ----------------
__global__ __launch_bounds__(256) void xpose_kernel(const float* __restrict__ x,
                                                    bf16* __restrict__ xT) {
  __shared__ float tile[64][65];
  const int blk = blockIdx.x;
  const int b = blk >> 4;
  const int n0 = (blk & 15) * 64;
  const int tid = threadIdx.x;
  {
    const int nl = tid & 63, dbase = (tid >> 6) * 16;
#pragma unroll
    for (int i = 0; i < 16; i++) {
      int d = dbase + i;
      tile[d][nl] = x[(size_t)(b * 64 + d) * 1024 + n0 + nl];
    }
  }
  __syncthreads();
  {
    const int dl = tid & 63, nbase = (tid >> 6) * 16;
#pragma unroll
    for (int i = 0; i < 16; i++) {
      int n = nbase + i;
      xT[(size_t)(b * 1024 + n0 + n) * 64 + dl] = (bf16)tile[dl][n];
    }
  }
}

// ---------------- KV producer: Kt (N,R) and Vn (R,N), sigmoid fused --------
// 128 tokens/block, 4 waves x 32 tokens. Input fragments hoisted (reused as
// A or B operand for both K and V). b64-packed stores.
template <int DIN>
__global__ __launch_bounds__(256) void kv_kernel(
    const bf16* __restrict__ inpT, const bf16* __restrict__ Wk,
    const bf16* __restrict__ Wv, bf16* __restrict__ Kt,
    bf16* __restrict__ Vn) {
  constexpr int SIN = DIN + 8;
  constexpr int KS = DIN / 16;
  __shared__ __attribute__((aligned(16))) bf16 inp_lds[128 * SIN];
  const int tid = threadIdx.x;
  const int lane = tid & 63, wv = tid >> 6;
  const int la = lane & 31, hi = lane >> 5;
  const int b = blockIdx.x >> 3;
  const int t0 = (blockIdx.x & 7) * 128;

  {
    constexpr int CPR = DIN / 8;
    for (int i = tid; i < 128 * CPR; i += 256) {
      int row = i / CPR, c = i % CPR;
      *(bf16x8*)&inp_lds[row * SIN + c * 8] =
          *(const bf16x8*)(inpT + (size_t)(b * 1024 + t0 + row) * DIN + c * 8);
    }
  }
  __syncthreads();

  bf16x8 fr[KS];  // wave's 32-token fragments (rows 32*wv+la, k-chunk hi)
#pragma unroll
  for (int ks = 0; ks < KS; ks++)
    fr[ks] = *(const bf16x8*)&inp_lds[(32 * wv + la) * SIN + hi * 8 + ks * 16];

  const int tokw = t0 + 32 * wv;

  // K: C[r][tok] = Wk(rows r) x inp(cols tok) -> Kt[tok][r], b64 over r
#pragma unroll
  for (int rt = 0; rt < 4; rt++) {
    f32x16 acc = ZERO16;
#pragma unroll
    for (int ks = 0; ks < KS; ks++) {
      bf16x8 wf = *(const bf16x8*)(Wk + (size_t)(la + 32 * rt) * DIN + hi * 8 + ks * 16);
      acc = MFMA32(wf, fr[ks], acc);
    }
#pragma unroll
    for (int g = 0; g < 4; g++) {
      bf16x4 pk;
#pragma unroll
      for (int i = 0; i < 4; i++) pk[i] = (bf16)fast_sigmoid(acc[4 * g + i]);
      int r0 = 32 * rt + 8 * g + 4 * hi;
      *(bf16x4*)(Kt + (size_t)(b * 1024 + tokw + la) * 128 + r0) = pk;
    }
  }
  // V: C[tok][r] = inp(rows tok) x Wv(cols r) -> Vn[r][tok], b64 over tok
#pragma unroll
  for (int rt = 0; rt < 4; rt++) {
    f32x16 acc = ZERO16;
#pragma unroll
    for (int ks = 0; ks < KS; ks++) {
      bf16x8 wf = *(const bf16x8*)(Wv + (size_t)(la + 32 * rt) * DIN + hi * 8 + ks * 16);
      acc = MFMA32(fr[ks], wf, acc);
    }
#pragma unroll
    for (int g = 0; g < 4; g++) {
      bf16x4 pk;
#pragma unroll
      for (int i = 0; i < 4; i++) pk[i] = (bf16)fast_sigmoid(acc[4 * g + i]);
      int tk0 = tokw + 8 * g + 4 * hi;
      *(bf16x4*)(Vn + (size_t)(b * 128 + la + 32 * rt) * 1024 + tk0) = pk;
    }
  }
}

// ---------------- flash: fused Q-gen + attention + projection --------------
// Block: 64 Q rows, sweeps 16 KV tiles of 64. 4 waves.
// S^T 2x2 grid: wave (ms=wv&1, ns=wv>>1) computes C[m 32][n 32], Q in regs.
// PV 2x2 grid: wave (ns2=wv&1, rrs=wv>>1) owns O[n 32][r 64].
template <int DIN>
__global__ __launch_bounds__(256, 3) void flash_kernel(
    const bf16* __restrict__ inpT, const bf16* __restrict__ Wq,
    const bf16* __restrict__ Kt, const bf16* __restrict__ Vn,
    const float* __restrict__ scale_inv, const int* __restrict__ L,
    const bf16* __restrict__ Wo, void* __restrict__ outp, int last) {
  // [0,17408) K_lds 64x136 | [17408,35840) V_lds 128x72 | [35840,45056) P 64x72
  // prologue: inp_stage@0, Q_lds@17408 (64x136)
  // epilogue: O_lds@0 (64x136), rs_partial f32[2][64]@17408, Lmask f32[64]@17920
  __shared__ __attribute__((aligned(16))) char smem[45056];
  bf16* K_lds = (bf16*)smem;
  bf16* V_lds = (bf16*)(smem + 17408);
  bf16* P_lds = (bf16*)(smem + 35840);

  const int tid = threadIdx.x;
  const int lane = tid & 63, wv = tid >> 6;
  const int la = lane & 31, hi = lane >> 5;
  const int b = blockIdx.x >> 4;
  const int q0 = (blockIdx.x & 15) * 64;

  const float inv = scale_inv[b];
  const float inv2 = inv * LOG2E;
  const float nb2 = -128.0f * inv2;  // exp2 arg <= 0 always (Q,K in (0,1))

  // ---- prologue: stage inp tile, compute Q = sigmoid(inp @ Wq^T) ----
  {
    constexpr int SIN = DIN + 8;
    constexpr int KSD = DIN / 16;
    bf16* inp_s = (bf16*)smem;
    constexpr int CPR = DIN / 8;
    for (int i = tid; i < 64 * CPR; i += 256) {
      int row = i / CPR, c = i % CPR;
      *(bf16x8*)&inp_s[row * SIN + c * 8] =
          *(const bf16x8*)(inpT + (size_t)(b * 1024 + q0 + row) * DIN + c * 8);
    }
    __syncthreads();
    bf16* Q_lds = (bf16*)(smem + 17408);
    bf16x8 wf[KSD];
#pragma unroll
    for (int ks = 0; ks < KSD; ks++)
      wf[ks] = *(const bf16x8*)(Wq + (size_t)(la + 32 * wv) * DIN + hi * 8 + ks * 16);
#pragma unroll
    for (int nt = 0; nt < 2; nt++) {
      f32x16 acc = ZERO16;
#pragma unroll
      for (int ks = 0; ks < KSD; ks++) {
        bf16x8 bfr = *(const bf16x8*)&inp_s[(la + 32 * nt) * SIN + hi * 8 + ks * 16];
        acc = MFMA32(wf[ks], bfr, acc);
      }
      // rows r = pat + 32*wv, col n = la + 32*nt -> Q_lds[n][r]
#pragma unroll
      for (int g = 0; g < 4; g++) {
        bf16x4 pk;
#pragma unroll
        for (int i = 0; i < 4; i++) pk[i] = (bf16)fast_sigmoid(acc[4 * g + i]);
        *(bf16x4*)((bf16*)(smem + 17408) + (size_t)(la + 32 * nt) * 136 +
                   32 * wv + 8 * g + 4 * hi) = pk;
      }
    }
    __syncthreads();
  }

  // Q fragments: B[k=r][n], wave's S n-slice = 32*(wv>>1)
  const int ms = wv & 1, ns = wv >> 1;
  bf16x8 qB[8];
#pragma unroll
  for (int ks = 0; ks < 8; ks++)
    qB[ks] = *(const bf16x8*)((bf16*)(smem + 17408) + (size_t)(32 * ns + la) * 136 +
                              hi * 8 + ks * 16);

  // staging geometry + first-tile prefetch
  const int krow = tid >> 4, kc = (tid & 15) * 8;
  const int vrow = tid >> 3, vc = (tid & 7) * 8;
  const bf16* kbase = Kt + (size_t)b * 1024 * 128;
  const bf16* vbase = Vn + (size_t)b * 128 * 1024;
  bf16x8 kr[4], vr[4];
#pragma unroll
  for (int p = 0; p < 4; p++) {
    kr[p] = *(const bf16x8*)(kbase + (size_t)(krow + 16 * p) * 128 + kc);
    vr[p] = *(const bf16x8*)(vbase + (size_t)(vrow + 32 * p) * 1024 + vc);
  }

  const int ns2 = wv & 1, rrs = wv >> 1;  // PV ownership
  f32x16 acc_o[2] = {ZERO16, ZERO16};
  float rs = 0.f;

  for (int it = 0; it < 16; it++) {
    __syncthreads();  // (A) everyone done reading prev tile
#pragma unroll
    for (int p = 0; p < 4; p++)
      *(bf16x8*)&K_lds[(krow + 16 * p) * 136 + kc] = kr[p];
#pragma unroll
    for (int p = 0; p < 4; p++)
      *(bf16x8*)&V_lds[(vrow + 32 * p) * 72 + vc] = vr[p];
    __syncthreads();  // (B) tile visible

    if (it < 15) {  // prefetch next tile into regs (hidden under S compute)
      const int m1 = (it + 1) * 64;
#pragma unroll
      for (int p = 0; p < 4; p++) {
        kr[p] = *(const bf16x8*)(kbase + (size_t)(m1 + krow + 16 * p) * 128 + kc);
        vr[p] = *(const bf16x8*)(vbase + (size_t)(vrow + 32 * p) * 1024 + m1 + vc);
      }
    }

    // S^T: C[m][n] = K(rows m, ms-slice) x Q(cols n, ns-slice)
    f32x16 sa = ZERO16;
#pragma unroll
    for (int ks = 0; ks < 8; ks++) {
      bf16x8 kf = *(const bf16x8*)&K_lds[(32 * ms + la) * 136 + hi * 8 + ks * 16];
      sa = MFMA32(kf, qB[ks], sa);
    }
    // exp + transposed P write: col n = 32*ns+la, rows m = i+8g+4hi+32ms
#pragma unroll
    for (int g = 0; g < 4; g++) {
      bf16x4 pk;
#pragma unroll
      for (int i = 0; i < 4; i++) {
        float p = exp2f(fmaf(sa[4 * g + i], inv2, nb2));
        rs += p;
        pk[i] = (bf16)p;
      }
      *(bf16x4*)&P_lds[(32 * ns + la) * 72 + 32 * ms + 8 * g + 4 * hi] = pk;
    }
    __syncthreads();  // (C) P complete (cross-wave)

    // PV: C[n][r] += P(rows n, ns2-slice) x V(cols r, rrs-slice)
    bf16x8 pA[4];
#pragma unroll
    for (int k2 = 0; k2 < 4; k2++)
      pA[k2] = *(const bf16x8*)&P_lds[(32 * ns2 + la) * 72 + hi * 8 + k2 * 16];
#pragma unroll
    for (int rt = 0; rt < 2; rt++) {
#pragma unroll
      for (int k2 = 0; k2 < 4; k2++) {
        bf16x8 vB = *(const bf16x8*)&V_lds[(64 * rrs + 32 * rt + la) * 72 +
                                           hi * 8 + k2 * 16];
        acc_o[rt] = MFMA32(pA[k2], vB, acc_o[rt]);
      }
    }
  }

  // ---- rowsums: lane has partial for col n=32*ns+la over its m rows ----
  rs += __shfl_xor(rs, 32, 64);  // combine hi halves
  __syncthreads();  // (D) all PV reads done
  float* rsp = (float*)(smem + 17408);  // [2][64] partial by ms
  if (lane < 32) rsp[ms * 64 + 32 * ns + la] = rs;
  float* Lm = (float*)(smem + 17920);
  if (!last && tid < 64) Lm[tid] = (float)L[b * 1024 + q0 + tid];
  __syncthreads();  // (E)

  // inverse sums for this wave's PV rows: n = 32*ns2 + 8g + 4hi + i
  f32x4 isum[4];
#pragma unroll
  for (int g = 0; g < 4; g++) {
    f32x4 a = *(f32x4*)&rsp[32 * ns2 + 8 * g + 4 * hi];
    f32x4 c = *(f32x4*)&rsp[64 + 32 * ns2 + 8 * g + 4 * hi];
#pragma unroll
    for (int i = 0; i < 4; i++) isum[g][i] = 1.0f / (a[i] + c[i]);
  }
  // normalize + assemble O_lds[n][r]
  bf16* O_lds = (bf16*)smem;
#pragma unroll
  for (int rt = 0; rt < 2; rt++) {
#pragma unroll
    for (int g = 0; g < 4; g++) {
#pragma unroll
      for (int i = 0; i < 4; i++) {
        int n = 32 * ns2 + 8 * g + 4 * hi + i;
        O_lds[(size_t)n * 136 + 64 * rrs + 32 * rt + la] =
            (bf16)(acc_o[rt][4 * g + i] * isum[g][i]);
      }
    }
  }
  __syncthreads();  // (F) O complete

  if (!last) {
    // inpT_next[n][o] = mask[n]*silu(sum_r O[n][r] Wo[o][r]); wave o-slice 32*wv
    bf16* out_b = (bf16*)outp;
    bf16x8 wB[8];
#pragma unroll
    for (int ks = 0; ks < 8; ks++)
      wB[ks] = *(const bf16x8*)(Wo + (size_t)(la + 32 * wv) * 128 + hi * 8 + ks * 16);
#pragma unroll
    for (int nt = 0; nt < 2; nt++) {
      f32x16 acc = ZERO16;
#pragma unroll
      for (int ks = 0; ks < 8; ks++) {
        bf16x8 oA = *(const bf16x8*)&O_lds[(la + 32 * nt) * 136 + hi * 8 + ks * 16];
        acc = MFMA32(oA, wB[ks], acc);
      }
#pragma unroll
      for (int g = 0; g < 4; g++) {
#pragma unroll
        for (int i = 0; i < 4; i++) {
          int n = 32 * nt + 8 * g + 4 * hi + i;
          float xv = acc[4 * g + i];
          float y = xv * fast_sigmoid(xv) * Lm[n];
          out_b[(size_t)(b * 1024 + q0 + n) * 128 + 32 * wv + la] = (bf16)y;
        }
      }
    }
  } else {
    // out[h][n] = silu(sum_r Wo[h][r] O[n][r]); wave (hs=wv&1, ns4=wv>>1)
    const int hs = wv & 1, ns4 = wv >> 1;
    float* outf = (float*)outp;
    bf16x8 wA[8];
#pragma unroll
    for (int ks = 0; ks < 8; ks++)
      wA[ks] = *(const bf16x8*)(Wo + (size_t)(la + 32 * hs) * 128 + hi * 8 + ks * 16);
    f32x16 acc = ZERO16;
#pragma unroll
    for (int ks = 0; ks < 8; ks++) {
      bf16x8 oB = *(const bf16x8*)&O_lds[(la + 32 * ns4) * 136 + hi * 8 + ks * 16];
      acc = MFMA32(wA[ks], oB, acc);
    }
#pragma unroll
    for (int g = 0; g < 4; g++) {
#pragma unroll
      for (int i = 0; i < 4; i++) {
        int h = 32 * hs + 8 * g + 4 * hi + i;
        float xv = acc[4 * g + i];
        outf[(size_t)(b * 64 + h) * 1024 + q0 + 32 * ns4 + la] =
            xv * fast_sigmoid(xv);
      }
    }
  }
}

// ---------------- host launch ----------------
extern "C" void kernel_launch(void* const* d_in, const int* in_sizes, int n_in,
                              void* d_out, int out_size, void* d_ws, size_t ws_size,
                              hipStream_t stream) {
  const float* x = (const float*)d_in[0];
  const int* L = (const int*)d_in[1];
  const float* wq0 = (const float*)d_in[2];
  const float* wqr = (const float*)d_in[3];
  const float* wk0 = (const float*)d_in[4];
  const float* wkr = (const float*)d_in[5];
  const float* wv0 = (const float*)d_in[6];
  const float* wvr = (const float*)d_in[7];
  const float* wor = (const float*)d_in[8];
  const float* wo_last = (const float*)d_in[9];

  // workspace layout (bytes)
  char* ws = (char*)d_ws;
  float* scale_inv = (float*)(ws + 0);            //    256 B
  bf16* wbf = (bf16*)(ws + 4096);                 // 327680 B
  bf16* xT = (bf16*)(ws + 335872);                //   8 MB  (B,N,64)
  bf16* inpT = (bf16*)(ws + 8724480);             //  16 MB  (B,N,128)
  bf16* Kt = (bf16*)(ws + 25501696);              //  16 MB  (B,N,128)
  bf16* Vn = (bf16*)(ws + 42278912);              //  16 MB  (B,128,N)
  if (ws_size < 59056128) return;                 // workspace too small

  prep_kernel<<<128, 256, 0, stream>>>(L, wq0, wqr, wk0, wkr, wv0, wvr, wor,
                                       wo_last, scale_inv, wbf);
  xpose_kernel<<<1024, 256, 0, stream>>>(x, xT);

  // bf16 weight offsets (elements) inside wbf:
  // wq0@0 wqr@8192 wk0@40960 wkr@49152 wv0@81920 wvr@90112 wor@122880 wo_last@155648
  for (int l = 0; l < 3; l++) {
    const bf16* Wq = (l == 0) ? wbf + 0 : wbf + 8192 + (size_t)(l - 1) * 16384;
    const bf16* Wk = (l == 0) ? wbf + 40960 : wbf + 49152 + (size_t)(l - 1) * 16384;
    const bf16* Wv = (l == 0) ? wbf + 81920 : wbf + 90112 + (size_t)(l - 1) * 16384;
    const bf16* Wo = (l < 2) ? wbf + 122880 + (size_t)l * 16384 : wbf + 155648;
    void* outp = (l < 2) ? (void*)inpT : (void*)d_out;
    if (l == 0) {
      kv_kernel<64><<<512, 256, 0, stream>>>(xT, Wk, Wv, Kt, Vn);
      flash_kernel<64><<<1024, 256, 0, stream>>>(xT, Wq, Kt, Vn, scale_inv, L,
                                                 Wo, outp, 0);
    } else {
      kv_kernel<128><<<512, 256, 0, stream>>>(inpT, Wk, Wv, Kt, Vn);
      flash_kernel<128><<<1024, 256, 0, stream>>>(inpT, Wq, Kt, Vn, scale_inv, L,
                                                  Wo, outp, (l == 2) ? 1 : 0);
    }
  }
}